// Round 1
// baseline (615.522 us; speedup 1.0000x reference)
//
#include <hip/hip_runtime.h>
#include <math.h>

constexpr int NN = 50000;
constexpr int EE = 800000;

#define LDS_BAR() asm volatile("s_waitcnt lgkmcnt(0)" ::: "memory")

__device__ __forceinline__ float wsum64(float v){
  #pragma unroll
  for (int m = 1; m < 64; m <<= 1) v += __shfl_xor(v, m);
  return v;
}
__device__ __forceinline__ float wmax64(float v){
  #pragma unroll
  for (int m = 1; m < 64; m <<= 1) v = fmaxf(v, __shfl_xor(v, m));
  return v;
}
__device__ __forceinline__ float sel4(int h, float a, float b, float c, float d){
  return h == 0 ? a : (h == 1 ? b : (h == 2 ? c : d));
}

__global__ void zero_i32(int* __restrict__ p, int n){
  int i = blockIdx.x * blockDim.x + threadIdx.x;
  if (i < n) p[i] = 0;
}

__global__ void hist_kernel(const int* __restrict__ ei, int* __restrict__ deg){
  int e = blockIdx.x * blockDim.x + threadIdx.x;
  if (e < EE) atomicAdd(&deg[ei[EE + e]], 1);
}

__global__ __launch_bounds__(1024) void scan_kernel(const int* __restrict__ deg,
                                                    int* __restrict__ row_ptr,
                                                    int* __restrict__ cursor, int n){
  __shared__ int wsums[16];
  int tid = threadIdx.x, lane = tid & 63, wid = tid >> 6;
  int carry = 0;
  if (tid == 0) row_ptr[0] = 0;
  for (int base = 0; base < n; base += 1024){
    int i = base + tid;
    int d = (i < n) ? deg[i] : 0;
    int v = d;
    #pragma unroll
    for (int off = 1; off < 64; off <<= 1){
      int t = __shfl_up(v, off);
      if (lane >= off) v += t;
    }
    if (lane == 63) wsums[wid] = v;
    __syncthreads();
    int woff = 0, tot = 0;
    #pragma unroll
    for (int w = 0; w < 16; w++){
      int s = wsums[w];
      if (w < wid) woff += s;
      tot += s;
    }
    int incl = woff + v;
    if (i < n){
      row_ptr[i + 1] = carry + incl;
      cursor[i]      = carry + incl - d;
    }
    carry += tot;
    __syncthreads();
  }
}

__global__ void fill_kernel(const int* __restrict__ ei, int* __restrict__ cursor,
                            int* __restrict__ col_src){
  int e = blockIdx.x * blockDim.x + threadIdx.x;
  if (e < EE){
    int src = ei[e], dst = ei[EE + e];
    int pos = atomicAdd(&cursor[dst], 1);
    col_src[pos] = src;
  }
}

// pack 4 weight matrices (each [96][K]) + biases into Wcat[384][K], bcat[384]
__global__ void pack_kernel(const float* __restrict__ Wq, const float* __restrict__ bq,
                            const float* __restrict__ Wk, const float* __restrict__ bk,
                            const float* __restrict__ Wv, const float* __restrict__ bv,
                            const float* __restrict__ Ws, const float* __restrict__ bs,
                            float* __restrict__ Wcat, float* __restrict__ bcat, int K){
  int c = blockIdx.x;            // 0..383
  int which = c / 96, r = c % 96;
  const float* Wsel = which == 0 ? Wq : which == 1 ? Wk : which == 2 ? Wv : Ws;
  const float* bsel = which == 0 ? bq : which == 1 ? bk : which == 2 ? bv : bs;
  for (int k = threadIdx.x; k < K; k += blockDim.x)
    Wcat[(size_t)c * K + k] = Wsel[(size_t)r * K + k];
  if (threadIdx.x == 0) bcat[c] = bsel[r];
}

// out[M][384] = A[M][K] @ Wcat[384][K]^T + bcat ; tile 128x128, thread 8x8
template<int K>
__global__ __launch_bounds__(256) void gemm_kernel(const float* __restrict__ A,
                                                   const float* __restrict__ Wcat,
                                                   const float* __restrict__ bcat,
                                                   float* __restrict__ out, int M){
  __shared__ float As[32][132];
  __shared__ float Bs[32][132];
  const int tid = threadIdx.x;
  const int rt = blockIdx.x * 128, ct = blockIdx.y * 128;
  const int ty = tid / 16, tx = tid % 16;
  float acc[8][8];
  #pragma unroll
  for (int i = 0; i < 8; i++)
    #pragma unroll
    for (int j = 0; j < 8; j++) acc[i][j] = 0.f;

  for (int kc = 0; kc < K; kc += 32){
    __syncthreads();
    #pragma unroll
    for (int p = 0; p < 4; p++){
      int r  = p * 32 + tid / 8;      // 0..127
      int k4 = (tid % 8) * 4;         // 0,4,...,28
      int grow = rt + r;
      float4 av = (grow < M) ? *(const float4*)(A + (size_t)grow * K + kc + k4)
                             : make_float4(0.f, 0.f, 0.f, 0.f);
      As[k4 + 0][r] = av.x; As[k4 + 1][r] = av.y; As[k4 + 2][r] = av.z; As[k4 + 3][r] = av.w;
      int gcol = ct + r;              // always < 384
      float4 bv = *(const float4*)(Wcat + (size_t)gcol * K + kc + k4);
      Bs[k4 + 0][r] = bv.x; Bs[k4 + 1][r] = bv.y; Bs[k4 + 2][r] = bv.z; Bs[k4 + 3][r] = bv.w;
    }
    __syncthreads();
    #pragma unroll
    for (int k = 0; k < 32; k++){
      float a[8], b[8];
      *(float4*)&a[0] = *(const float4*)&As[k][ty * 8];
      *(float4*)&a[4] = *(const float4*)&As[k][ty * 8 + 4];
      *(float4*)&b[0] = *(const float4*)&Bs[k][tx * 8];
      *(float4*)&b[4] = *(const float4*)&Bs[k][tx * 8 + 4];
      #pragma unroll
      for (int i = 0; i < 8; i++)
        #pragma unroll
        for (int j = 0; j < 8; j++) acc[i][j] = fmaf(a[i], b[j], acc[i][j]);
    }
  }
  #pragma unroll
  for (int i = 0; i < 8; i++){
    int grow = rt + ty * 8 + i;
    if (grow < M){
      #pragma unroll
      for (int j = 0; j < 8; j++){
        int gcol = ct + tx * 8 + j;
        out[(size_t)grow * 384 + gcol] = acc[i][j] + bcat[gcol];
      }
    }
  }
}

// one wave per node. qkvs row: q[0:96] k[96:192] v[192:288] s[288:384]
// mode 0: gating + exact GELU -> outp ; mode 1: gating + LayerNorm -> outp
__global__ __launch_bounds__(256) void attn_kernel(
    const float* __restrict__ qkvs, const int* __restrict__ row_ptr,
    const int* __restrict__ col_src, const float* __restrict__ Wb,
    const float* __restrict__ gamma, const float* __restrict__ beta,
    float* __restrict__ outp, int mode){
  __shared__ float qsh[4][96];
  __shared__ float esh[4][64][4];
  __shared__ int   ssh[4][64];
  const int lane = threadIdx.x & 63;
  const int wid  = threadIdx.x >> 6;
  const int n = blockIdx.x * 4 + wid;
  if (n >= NN) return;
  const float* base = qkvs + (size_t)n * 384;
  qsh[wid][lane] = base[lane];
  if (lane < 32) qsh[wid][64 + lane] = base[64 + lane];
  LDS_BAR();
  const int rs = row_ptr[n], re = row_ptr[n + 1];
  const int h0 = lane / 24;              // head of feature `lane`    (0..2)
  const int h1 = (64 + lane) / 24;       // head of feature `64+lane` (2..3)
  float m0 = -INFINITY, m1 = -INFINITY, m2 = -INFINITY, m3 = -INFINITY;
  float s0 = 0.f, s1 = 0.f, s2 = 0.f, s3 = 0.f;
  float acc0 = 0.f, acc1 = 0.f;

  for (int cb = rs; cb < re; cb += 64){
    int j = cb + lane;
    bool act = j < re;
    int src = act ? col_src[j] : 0;
    const float4* kp = (const float4*)(qkvs + (size_t)src * 384 + 96);
    float al[4];
    #pragma unroll
    for (int h = 0; h < 4; h++){
      float dot = 0.f;
      #pragma unroll
      for (int c4 = 0; c4 < 6; c4++){
        float4 kv = kp[h * 6 + c4];
        dot = fmaf(qsh[wid][h * 24 + c4 * 4 + 0], kv.x, dot);
        dot = fmaf(qsh[wid][h * 24 + c4 * 4 + 1], kv.y, dot);
        dot = fmaf(qsh[wid][h * 24 + c4 * 4 + 2], kv.z, dot);
        dot = fmaf(qsh[wid][h * 24 + c4 * 4 + 3], kv.w, dot);
      }
      al[h] = act ? dot * 0.2041241452319315f : -INFINITY;
    }
    float nm0 = fmaxf(m0, wmax64(al[0]));
    float nm1 = fmaxf(m1, wmax64(al[1]));
    float nm2 = fmaxf(m2, wmax64(al[2]));
    float nm3 = fmaxf(m3, wmax64(al[3]));
    float r0 = __expf(m0 - nm0), r1 = __expf(m1 - nm1);
    float r2 = __expf(m2 - nm2), r3 = __expf(m3 - nm3);
    float e0 = __expf(al[0] - nm0);   // -inf -> 0 for inactive lanes
    float e1 = __expf(al[1] - nm1);
    float e2 = __expf(al[2] - nm2);
    float e3 = __expf(al[3] - nm3);
    s0 = s0 * r0 + wsum64(e0);
    s1 = s1 * r1 + wsum64(e1);
    s2 = s2 * r2 + wsum64(e2);
    s3 = s3 * r3 + wsum64(e3);
    acc0 *= sel4(h0, r0, r1, r2, r3);
    if (lane < 32) acc1 *= sel4(h1, r0, r1, r2, r3);
    esh[wid][lane][0] = e0; esh[wid][lane][1] = e1;
    esh[wid][lane][2] = e2; esh[wid][lane][3] = e3;
    ssh[wid][lane] = src;
    LDS_BAR();
    int cn = min(64, re - cb);
    for (int t = 0; t < cn; t++){
      int sb = ssh[wid][t];
      const float* vp = qkvs + (size_t)sb * 384 + 192;
      float w0 = esh[wid][t][h0];
      acc0 = fmaf(w0, vp[lane], acc0);
      if (lane < 32){
        float w1 = esh[wid][t][h1];
        acc1 = fmaf(w1, vp[64 + lane], acc1);
      }
    }
    LDS_BAR();
    m0 = nm0; m1 = nm1; m2 = nm2; m3 = nm3;
  }

  float inv0 = 0.f, inv1 = 0.f;
  if (re > rs){
    inv0 = 1.0f / sel4(h0, s0, s1, s2, s3);
    if (lane < 32) inv1 = 1.0f / sel4(h1, s0, s1, s2, s3);
  }
  float o0 = acc0 * inv0;
  float o1 = (lane < 32) ? acc1 * inv1 : 0.f;
  float xr0 = base[288 + lane];
  float xr1 = (lane < 32) ? base[288 + 64 + lane] : 0.f;
  float p = Wb[lane] * o0 + Wb[96 + lane] * xr0 + Wb[192 + lane] * (o0 - xr0);
  if (lane < 32)
    p += Wb[64 + lane] * o1 + Wb[160 + lane] * xr1 + Wb[256 + lane] * (o1 - xr1);
  float gd = wsum64(p);
  float g = 1.0f / (1.0f + __expf(-gd));
  float y0 = g * xr0 + (1.0f - g) * o0;
  float y1 = g * xr1 + (1.0f - g) * o1;
  if (mode == 0){
    y0 = 0.5f * y0 * (1.0f + erff(y0 * 0.7071067811865475f));
    y1 = 0.5f * y1 * (1.0f + erff(y1 * 0.7071067811865475f));
    outp[(size_t)n * 96 + lane] = y0;
    if (lane < 32) outp[(size_t)n * 96 + 64 + lane] = y1;
  } else {
    float msum = wsum64(y0 + ((lane < 32) ? y1 : 0.f));
    float mu = msum * (1.0f / 96.0f);
    float d0 = y0 - mu, d1 = y1 - mu;
    float vs = wsum64(d0 * d0 + ((lane < 32) ? d1 * d1 : 0.f));
    float inv = rsqrtf(vs * (1.0f / 96.0f) + 1e-5f);
    outp[(size_t)n * 96 + lane] = d0 * inv * gamma[lane] + beta[lane];
    if (lane < 32)
      outp[(size_t)n * 96 + 64 + lane] = d1 * inv * gamma[64 + lane] + beta[64 + lane];
  }
}

extern "C" void kernel_launch(void* const* d_in, const int* in_sizes, int n_in,
                              void* d_out, int out_size, void* d_ws, size_t ws_size,
                              hipStream_t stream){
  const float* x    = (const float*)d_in[0];
  const int*   ei   = (const int*)d_in[1];
  const float* Wq1  = (const float*)d_in[2];
  const float* bq1  = (const float*)d_in[3];
  const float* Wk1  = (const float*)d_in[4];
  const float* bk1  = (const float*)d_in[5];
  const float* Wv1  = (const float*)d_in[6];
  const float* bv1  = (const float*)d_in[7];
  const float* Ws1  = (const float*)d_in[8];
  const float* bs1  = (const float*)d_in[9];
  const float* Wb1  = (const float*)d_in[10];
  const float* Wq2  = (const float*)d_in[11];
  const float* bq2  = (const float*)d_in[12];
  const float* Wk2  = (const float*)d_in[13];
  const float* bk2  = (const float*)d_in[14];
  const float* Wv2  = (const float*)d_in[15];
  const float* bv2  = (const float*)d_in[16];
  const float* Ws2  = (const float*)d_in[17];
  const float* bs2  = (const float*)d_in[18];
  const float* Wb2  = (const float*)d_in[19];
  const float* gamma = (const float*)d_in[20];
  const float* beta  = (const float*)d_in[21];
  float* out = (float*)d_out;

  char* ws = (char*)d_ws;
  size_t off = 0;
  auto take = [&](size_t b) -> void* {
    void* p = ws + off;
    off += (b + 255) & ~(size_t)255;
    return p;
  };
  float* qkvs  = (float*)take((size_t)NN * 384 * 4);
  float* h1    = (float*)take((size_t)NN * 96 * 4);
  float* Wcat  = (float*)take((size_t)384 * 128 * 4);
  float* bcat  = (float*)take(384 * 4);
  int* deg     = (int*)take((size_t)NN * 4);
  int* cursor  = (int*)take((size_t)NN * 4);
  int* row_ptr = (int*)take((size_t)(NN + 1) * 4);
  int* col_src = (int*)take((size_t)EE * 4);

  // CSR build (shared by both layers)
  zero_i32<<<(NN + 255) / 256, 256, 0, stream>>>(deg, NN);
  hist_kernel<<<(EE + 255) / 256, 256, 0, stream>>>(ei, deg);
  scan_kernel<<<1, 1024, 0, stream>>>(deg, row_ptr, cursor, NN);
  fill_kernel<<<(EE + 255) / 256, 256, 0, stream>>>(ei, cursor, col_src);

  dim3 gg((NN + 127) / 128, 3);
  // layer 1
  pack_kernel<<<384, 128, 0, stream>>>(Wq1, bq1, Wk1, bk1, Wv1, bv1, Ws1, bs1, Wcat, bcat, 128);
  gemm_kernel<128><<<gg, 256, 0, stream>>>(x, Wcat, bcat, qkvs, NN);
  attn_kernel<<<(NN + 3) / 4, 256, 0, stream>>>(qkvs, row_ptr, col_src, Wb1,
                                                nullptr, nullptr, h1, 0);
  // layer 2
  pack_kernel<<<384, 128, 0, stream>>>(Wq2, bq2, Wk2, bk2, Wv2, bv2, Ws2, bs2, Wcat, bcat, 96);
  gemm_kernel<96><<<gg, 256, 0, stream>>>(h1, Wcat, bcat, qkvs, NN);
  attn_kernel<<<(NN + 3) / 4, 256, 0, stream>>>(qkvs, row_ptr, col_src, Wb2,
                                                gamma, beta, out, 1);
}

// Round 2
// 474.509 us; speedup vs baseline: 1.2972x; 1.2972x over previous
//
#include <hip/hip_runtime.h>
#include <hip/hip_bf16.h>
#include <math.h>

constexpr int NN = 50000;
constexpr int EE = 800000;

__device__ __forceinline__ float bl16(unsigned int u){ return __uint_as_float(u << 16); }
__device__ __forceinline__ float bh16(unsigned int u){ return __uint_as_float(u & 0xffff0000u); }

__global__ void zero_i32(int* __restrict__ p, int n){
  int i = blockIdx.x * blockDim.x + threadIdx.x;
  if (i < n) p[i] = 0;
}

__global__ void hist_kernel(const int* __restrict__ ei, int* __restrict__ deg){
  int e = blockIdx.x * blockDim.x + threadIdx.x;
  if (e < EE) atomicAdd(&deg[ei[EE + e]], 1);
}

__global__ __launch_bounds__(1024) void scan_kernel(const int* __restrict__ deg,
                                                    int* __restrict__ row_ptr,
                                                    int* __restrict__ cursor, int n){
  __shared__ int wsums[16];
  int tid = threadIdx.x, lane = tid & 63, wid = tid >> 6;
  int carry = 0;
  if (tid == 0) row_ptr[0] = 0;
  for (int base = 0; base < n; base += 1024){
    int i = base + tid;
    int d = (i < n) ? deg[i] : 0;
    int v = d;
    #pragma unroll
    for (int off = 1; off < 64; off <<= 1){
      int t = __shfl_up(v, off);
      if (lane >= off) v += t;
    }
    if (lane == 63) wsums[wid] = v;
    __syncthreads();
    int woff = 0, tot = 0;
    #pragma unroll
    for (int w = 0; w < 16; w++){
      int s = wsums[w];
      if (w < wid) woff += s;
      tot += s;
    }
    int incl = woff + v;
    if (i < n){
      row_ptr[i + 1] = carry + incl;
      cursor[i]      = carry + incl - d;
    }
    carry += tot;
    __syncthreads();
  }
}

__global__ void fill_kernel(const int* __restrict__ ei, int* __restrict__ cursor,
                            int* __restrict__ col_src){
  int e = blockIdx.x * blockDim.x + threadIdx.x;
  if (e < EE){
    int src = ei[e], dst = ei[EE + e];
    int pos = atomicAdd(&cursor[dst], 1);
    col_src[pos] = src;
  }
}

// pack 4 weight matrices (each [96][K]) + biases into Wcat[384][K], bcat[384]
__global__ void pack_kernel(const float* __restrict__ Wq, const float* __restrict__ bq,
                            const float* __restrict__ Wk, const float* __restrict__ bk,
                            const float* __restrict__ Wv, const float* __restrict__ bv,
                            const float* __restrict__ Ws, const float* __restrict__ bs,
                            float* __restrict__ Wcat, float* __restrict__ bcat, int K){
  int c = blockIdx.x;            // 0..383
  int which = c / 96, r = c % 96;
  const float* Wsel = which == 0 ? Wq : which == 1 ? Wk : which == 2 ? Wv : Ws;
  const float* bsel = which == 0 ? bq : which == 1 ? bk : which == 2 ? bv : bs;
  for (int k = threadIdx.x; k < K; k += blockDim.x)
    Wcat[(size_t)c * K + k] = Wsel[(size_t)r * K + k];
  if (threadIdx.x == 0) bcat[c] = bsel[r];
}

// C[M][384] = A[M][K] @ Wcat[384][K]^T + bcat
// epilogue splits: cols 0-95 -> qs[.][0:96] f32 (q); 96-191 -> kv[.][0:96] bf16 (k);
// 192-287 -> kv[.][96:192] bf16 (v); 288-383 -> qs[.][96:192] f32 (skip)
template<int K>
__global__ __launch_bounds__(256) void gemm_kernel(const float* __restrict__ A,
                                                   const float* __restrict__ Wcat,
                                                   const float* __restrict__ bcat,
                                                   float* __restrict__ qs,
                                                   __hip_bfloat16* __restrict__ kvb,
                                                   int M){
  __shared__ float As[32][132];
  __shared__ float Bs[32][132];
  const int tid = threadIdx.x;
  const int rt = blockIdx.x * 128, ct = blockIdx.y * 128;
  const int ty = tid / 16, tx = tid % 16;
  float acc[8][8];
  #pragma unroll
  for (int i = 0; i < 8; i++)
    #pragma unroll
    for (int j = 0; j < 8; j++) acc[i][j] = 0.f;

  for (int kc = 0; kc < K; kc += 32){
    __syncthreads();
    #pragma unroll
    for (int p = 0; p < 4; p++){
      int r  = p * 32 + tid / 8;      // 0..127
      int k4 = (tid % 8) * 4;         // 0,4,...,28
      int grow = rt + r;
      float4 av = (grow < M) ? *(const float4*)(A + (size_t)grow * K + kc + k4)
                             : make_float4(0.f, 0.f, 0.f, 0.f);
      As[k4 + 0][r] = av.x; As[k4 + 1][r] = av.y; As[k4 + 2][r] = av.z; As[k4 + 3][r] = av.w;
      int gcol = ct + r;              // always < 384
      float4 bv = *(const float4*)(Wcat + (size_t)gcol * K + kc + k4);
      Bs[k4 + 0][r] = bv.x; Bs[k4 + 1][r] = bv.y; Bs[k4 + 2][r] = bv.z; Bs[k4 + 3][r] = bv.w;
    }
    __syncthreads();
    #pragma unroll
    for (int k = 0; k < 32; k++){
      float a[8], b[8];
      *(float4*)&a[0] = *(const float4*)&As[k][ty * 8];
      *(float4*)&a[4] = *(const float4*)&As[k][ty * 8 + 4];
      *(float4*)&b[0] = *(const float4*)&Bs[k][tx * 8];
      *(float4*)&b[4] = *(const float4*)&Bs[k][tx * 8 + 4];
      #pragma unroll
      for (int i = 0; i < 8; i++)
        #pragma unroll
        for (int j = 0; j < 8; j++) acc[i][j] = fmaf(a[i], b[j], acc[i][j]);
    }
  }
  #pragma unroll
  for (int i = 0; i < 8; i++){
    int grow = rt + ty * 8 + i;
    if (grow < M){
      #pragma unroll
      for (int j = 0; j < 8; j++){
        int gcol = ct + tx * 8 + j;
        float val = acc[i][j] + bcat[gcol];
        if (gcol < 96)       qs[(size_t)grow * 192 + gcol] = val;
        else if (gcol < 192) kvb[(size_t)grow * 192 + (gcol - 96)] = __float2bfloat16(val);
        else if (gcol < 288) kvb[(size_t)grow * 192 + 96 + (gcol - 192)] = __float2bfloat16(val);
        else                 qs[(size_t)grow * 192 + 96 + (gcol - 288)] = val;
      }
    }
  }
}

// one wave per node; chunk of 16 edges.
// alpha role: lane = 4*g + h -> edge g (0..15), head h (0..3); 4-lane group reads one
//   coalesced 192B bf16 k-row. per-head softmax reductions via shfl_xor {4,8,16,32}.
// V role: lane = 16*vg + l -> edge residue vg (mod 4), features 6l..6l+5 (head l>>2);
//   16-lane group reads one coalesced 192B bf16 v-row. e/src moved via __shfl (no LDS).
__global__ __launch_bounds__(256) void attn_kernel(
    const float* __restrict__ qs, const __hip_bfloat16* __restrict__ kv,
    const int* __restrict__ row_ptr, const int* __restrict__ col_src,
    const float* __restrict__ Wb, const float* __restrict__ gamma,
    const float* __restrict__ beta, float* __restrict__ outp, int mode){
  const int lane = threadIdx.x & 63;
  const int wid  = threadIdx.x >> 6;
  const int n = blockIdx.x * 4 + wid;
  if (n >= NN) return;
  const int h_a = lane & 3;
  const int g_a = lane >> 2;
  const int l_v = lane & 15;
  const int vg  = lane >> 4;
  const int h_v = l_v >> 2;

  // q fragment for head h_a (24 floats), broadcast across the 16 lanes sharing h_a
  float qr[24];
  {
    const float* qrow = qs + (size_t)n * 192 + h_a * 24;
    #pragma unroll
    for (int i = 0; i < 6; i++){
      float4 t = *(const float4*)(qrow + 4 * i);
      qr[4*i+0] = t.x; qr[4*i+1] = t.y; qr[4*i+2] = t.z; qr[4*i+3] = t.w;
    }
  }
  const int rs = row_ptr[n], re = row_ptr[n + 1];
  float m = -INFINITY, s = 0.f;
  float acc[6] = {0.f, 0.f, 0.f, 0.f, 0.f, 0.f};

  for (int cb = rs; cb < re; cb += 16){
    const int cn = re - cb;             // >=1
    // ---- alpha ----
    bool act = g_a < cn;
    int srcv = 0;
    float al = -INFINITY;
    if (act){
      srcv = col_src[cb + g_a];
      const uint4* kp = (const uint4*)((const char*)kv + (size_t)srcv * 384 + h_a * 48);
      float dot = 0.f;
      #pragma unroll
      for (int w = 0; w < 3; w++){
        uint4 u = kp[w];
        dot = fmaf(qr[w*8+0], bl16(u.x), dot); dot = fmaf(qr[w*8+1], bh16(u.x), dot);
        dot = fmaf(qr[w*8+2], bl16(u.y), dot); dot = fmaf(qr[w*8+3], bh16(u.y), dot);
        dot = fmaf(qr[w*8+4], bl16(u.z), dot); dot = fmaf(qr[w*8+5], bh16(u.z), dot);
        dot = fmaf(qr[w*8+6], bl16(u.w), dot); dot = fmaf(qr[w*8+7], bh16(u.w), dot);
      }
      al = dot * 0.2041241452319315f;
    }
    // per-head chunk max / sum over the 16 edges (stride-4 lanes)
    float cm = al;
    cm = fmaxf(cm, __shfl_xor(cm, 4));
    cm = fmaxf(cm, __shfl_xor(cm, 8));
    cm = fmaxf(cm, __shfl_xor(cm, 16));
    cm = fmaxf(cm, __shfl_xor(cm, 32));
    float nm = fmaxf(m, cm);
    float r  = __expf(m - nm);          // first chunk: exp(-inf)=0
    float e  = __expf(al - nm);         // inactive lanes: 0
    float cs = e;
    cs += __shfl_xor(cs, 4);
    cs += __shfl_xor(cs, 8);
    cs += __shfl_xor(cs, 16);
    cs += __shfl_xor(cs, 32);
    s = s * r + cs;
    m = nm;
    // ---- V accumulation ----
    float rv = __shfl(r, h_v);          // lane h (0..3) holds head h
    #pragma unroll
    for (int i = 0; i < 6; i++) acc[i] *= rv;
    #pragma unroll
    for (int st = 0; st < 4; st++){
      int eidx = st * 4 + vg;
      int sl = 4 * eidx + h_v;
      float w  = __shfl(e, sl);
      int   sb = __shfl(srcv, sl);
      if (eidx < cn){
        const unsigned int* vp =
          (const unsigned int*)((const char*)kv + (size_t)sb * 384 + 192 + 12 * l_v);
        unsigned int u0 = vp[0], u1 = vp[1], u2 = vp[2];
        acc[0] = fmaf(w, bl16(u0), acc[0]); acc[1] = fmaf(w, bh16(u0), acc[1]);
        acc[2] = fmaf(w, bl16(u1), acc[2]); acc[3] = fmaf(w, bh16(u1), acc[3]);
        acc[4] = fmaf(w, bl16(u2), acc[4]); acc[5] = fmaf(w, bh16(u2), acc[5]);
      }
    }
  }

  // combine the 4 edge-residue groups
  #pragma unroll
  for (int i = 0; i < 6; i++){
    acc[i] += __shfl_xor(acc[i], 16);
    acc[i] += __shfl_xor(acc[i], 32);
  }
  float sv  = __shfl(s, h_v);
  float inv = (re > rs) ? 1.0f / sv : 0.f;
  float o[6], xr[6];
  #pragma unroll
  for (int i = 0; i < 6; i++) o[i] = acc[i] * inv;
  const float* xrp = qs + (size_t)n * 192 + 96 + 6 * l_v;
  #pragma unroll
  for (int i = 0; i < 6; i++) xr[i] = xrp[i];

  float p = 0.f;
  #pragma unroll
  for (int i = 0; i < 6; i++){
    int f = 6 * l_v + i;
    p += Wb[f] * o[i] + Wb[96 + f] * xr[i] + Wb[192 + f] * (o[i] - xr[i]);
  }
  p += __shfl_xor(p, 1);
  p += __shfl_xor(p, 2);
  p += __shfl_xor(p, 4);
  p += __shfl_xor(p, 8);
  float g = 1.0f / (1.0f + __expf(-p));
  float y[6];
  #pragma unroll
  for (int i = 0; i < 6; i++) y[i] = g * xr[i] + (1.0f - g) * o[i];

  if (mode == 0){
    #pragma unroll
    for (int i = 0; i < 6; i++)
      y[i] = 0.5f * y[i] * (1.0f + erff(y[i] * 0.7071067811865475f));
    if (vg == 0){
      float* op = outp + (size_t)n * 96 + 6 * l_v;
      #pragma unroll
      for (int i = 0; i < 6; i++) op[i] = y[i];
    }
  } else {
    float ssum = y[0] + y[1] + y[2] + y[3] + y[4] + y[5];
    ssum += __shfl_xor(ssum, 1);
    ssum += __shfl_xor(ssum, 2);
    ssum += __shfl_xor(ssum, 4);
    ssum += __shfl_xor(ssum, 8);
    float mu = ssum * (1.0f / 96.0f);
    float vsum = 0.f;
    #pragma unroll
    for (int i = 0; i < 6; i++){ float d = y[i] - mu; vsum += d * d; }
    vsum += __shfl_xor(vsum, 1);
    vsum += __shfl_xor(vsum, 2);
    vsum += __shfl_xor(vsum, 4);
    vsum += __shfl_xor(vsum, 8);
    float invs = rsqrtf(vsum * (1.0f / 96.0f) + 1e-5f);
    if (vg == 0){
      float* op = outp + (size_t)n * 96 + 6 * l_v;
      #pragma unroll
      for (int i = 0; i < 6; i++){
        int f = 6 * l_v + i;
        op[i] = (y[i] - mu) * invs * gamma[f] + beta[f];
      }
    }
  }
}

extern "C" void kernel_launch(void* const* d_in, const int* in_sizes, int n_in,
                              void* d_out, int out_size, void* d_ws, size_t ws_size,
                              hipStream_t stream){
  const float* x    = (const float*)d_in[0];
  const int*   ei   = (const int*)d_in[1];
  const float* Wq1  = (const float*)d_in[2];
  const float* bq1  = (const float*)d_in[3];
  const float* Wk1  = (const float*)d_in[4];
  const float* bk1  = (const float*)d_in[5];
  const float* Wv1  = (const float*)d_in[6];
  const float* bv1  = (const float*)d_in[7];
  const float* Ws1  = (const float*)d_in[8];
  const float* bs1  = (const float*)d_in[9];
  const float* Wb1  = (const float*)d_in[10];
  const float* Wq2  = (const float*)d_in[11];
  const float* bq2  = (const float*)d_in[12];
  const float* Wk2  = (const float*)d_in[13];
  const float* bk2  = (const float*)d_in[14];
  const float* Wv2  = (const float*)d_in[15];
  const float* bv2  = (const float*)d_in[16];
  const float* Ws2  = (const float*)d_in[17];
  const float* bs2  = (const float*)d_in[18];
  const float* Wb2  = (const float*)d_in[19];
  const float* gamma = (const float*)d_in[20];
  const float* beta  = (const float*)d_in[21];
  float* out = (float*)d_out;

  char* ws = (char*)d_ws;
  size_t off = 0;
  auto take = [&](size_t b) -> void* {
    void* p = ws + off;
    off += (b + 255) & ~(size_t)255;
    return p;
  };
  float* qs            = (float*)take((size_t)NN * 192 * 4);
  __hip_bfloat16* kvb  = (__hip_bfloat16*)take((size_t)NN * 192 * 2);
  float* h1            = (float*)take((size_t)NN * 96 * 4);
  float* Wcat          = (float*)take((size_t)384 * 128 * 4);
  float* bcat          = (float*)take(384 * 4);
  int* deg             = (int*)take((size_t)NN * 4);
  int* cursor          = (int*)take((size_t)NN * 4);
  int* row_ptr         = (int*)take((size_t)(NN + 1) * 4);
  int* col_src         = (int*)take((size_t)EE * 4);

  // CSR build (shared by both layers)
  zero_i32<<<(NN + 255) / 256, 256, 0, stream>>>(deg, NN);
  hist_kernel<<<(EE + 255) / 256, 256, 0, stream>>>(ei, deg);
  scan_kernel<<<1, 1024, 0, stream>>>(deg, row_ptr, cursor, NN);
  fill_kernel<<<(EE + 255) / 256, 256, 0, stream>>>(ei, cursor, col_src);

  dim3 gg((NN + 127) / 128, 3);
  // layer 1
  pack_kernel<<<384, 128, 0, stream>>>(Wq1, bq1, Wk1, bk1, Wv1, bv1, Ws1, bs1, Wcat, bcat, 128);
  gemm_kernel<128><<<gg, 256, 0, stream>>>(x, Wcat, bcat, qs, kvb, NN);
  attn_kernel<<<(NN + 3) / 4, 256, 0, stream>>>(qs, kvb, row_ptr, col_src, Wb1,
                                                nullptr, nullptr, h1, 0);
  // layer 2
  pack_kernel<<<384, 128, 0, stream>>>(Wq2, bq2, Wk2, bk2, Wv2, bv2, Ws2, bs2, Wcat, bcat, 96);
  gemm_kernel<96><<<gg, 256, 0, stream>>>(h1, Wcat, bcat, qs, kvb, NN);
  attn_kernel<<<(NN + 3) / 4, 256, 0, stream>>>(qs, kvb, row_ptr, col_src, Wb2,
                                                gamma, beta, out, 1);
}

// Round 3
// 358.608 us; speedup vs baseline: 1.7164x; 1.3232x over previous
//
#include <hip/hip_runtime.h>
#include <hip/hip_bf16.h>
#include <math.h>

constexpr int NN = 50000;
constexpr int EE = 800000;

typedef short v8s __attribute__((ext_vector_type(8)));
typedef float v4f __attribute__((ext_vector_type(4)));

__device__ __forceinline__ float bl16(unsigned int u){ return __uint_as_float(u << 16); }
__device__ __forceinline__ float bh16(unsigned int u){ return __uint_as_float(u & 0xffff0000u); }
__device__ __forceinline__ short f2b(float f){
  __hip_bfloat16 h = __float2bfloat16(f);
  return *reinterpret_cast<short*>(&h);
}

__global__ void zero_i32(int* __restrict__ p, int n){
  int i = blockIdx.x * blockDim.x + threadIdx.x;
  if (i < n) p[i] = 0;
}

__global__ void hist_kernel(const int* __restrict__ ei, int* __restrict__ deg){
  int e = blockIdx.x * blockDim.x + threadIdx.x;
  if (e < EE) atomicAdd(&deg[ei[EE + e]], 1);
}

__global__ __launch_bounds__(1024) void scan_kernel(const int* __restrict__ deg,
                                                    int* __restrict__ row_ptr,
                                                    int* __restrict__ cursor, int n){
  __shared__ int wsums[16];
  int tid = threadIdx.x, lane = tid & 63, wid = tid >> 6;
  int carry = 0;
  if (tid == 0) row_ptr[0] = 0;
  for (int base = 0; base < n; base += 1024){
    int i = base + tid;
    int d = (i < n) ? deg[i] : 0;
    int v = d;
    #pragma unroll
    for (int off = 1; off < 64; off <<= 1){
      int t = __shfl_up(v, off);
      if (lane >= off) v += t;
    }
    if (lane == 63) wsums[wid] = v;
    __syncthreads();
    int woff = 0, tot = 0;
    #pragma unroll
    for (int w = 0; w < 16; w++){
      int s = wsums[w];
      if (w < wid) woff += s;
      tot += s;
    }
    int incl = woff + v;
    if (i < n){
      row_ptr[i + 1] = carry + incl;
      cursor[i]      = carry + incl - d;
    }
    carry += tot;
    __syncthreads();
  }
}

__global__ void fill_kernel(const int* __restrict__ ei, int* __restrict__ cursor,
                            int* __restrict__ col_src){
  int e = blockIdx.x * blockDim.x + threadIdx.x;
  if (e < EE){
    int src = ei[e], dst = ei[EE + e];
    int pos = atomicAdd(&cursor[dst], 1);
    col_src[pos] = src;
  }
}

__global__ void cast_kernel(const float* __restrict__ in, short* __restrict__ out, int n8){
  int i = blockIdx.x * blockDim.x + threadIdx.x;
  if (i >= n8) return;
  float4 a = ((const float4*)in)[2 * i];
  float4 b = ((const float4*)in)[2 * i + 1];
  v8s o;
  o[0] = f2b(a.x); o[1] = f2b(a.y); o[2] = f2b(a.z); o[3] = f2b(a.w);
  o[4] = f2b(b.x); o[5] = f2b(b.y); o[6] = f2b(b.z); o[7] = f2b(b.w);
  ((v8s*)out)[i] = o;
}

// pack 4 weight matrices (each [96][K] f32) + biases into bf16 Wcat[384][K], f32 bcat[384]
__global__ void pack_kernel(const float* __restrict__ Wq, const float* __restrict__ bq,
                            const float* __restrict__ Wk, const float* __restrict__ bk,
                            const float* __restrict__ Wv, const float* __restrict__ bv,
                            const float* __restrict__ Ws, const float* __restrict__ bs,
                            short* __restrict__ Wcat, float* __restrict__ bcat, int K){
  int c = blockIdx.x;            // 0..383
  int which = c / 96, r = c % 96;
  const float* Wsel = which == 0 ? Wq : which == 1 ? Wk : which == 2 ? Wv : Ws;
  const float* bsel = which == 0 ? bq : which == 1 ? bk : which == 2 ? bv : bs;
  for (int k = threadIdx.x; k < K; k += blockDim.x)
    Wcat[(size_t)c * K + k] = f2b(Wsel[(size_t)r * K + k]);
  if (threadIdx.x == 0) bcat[c] = bsel[r];
}

// C[M][384] = A[M][K](bf16) @ Wcat[384][K](bf16)^T + bcat, via mfma_f32_16x16x32_bf16.
// 128x128 tile, 4 waves 2x2, 64x64 per wave = 4x4 fragments. Whole K staged in LDS once.
// Epilogue split: cols 0-95 -> qs[.][0:96] f32 (q); 96-191 -> kv[.][0:96] bf16 (k);
// 192-287 -> kv[.][96:192] bf16 (v); 288-383 -> qs[.][96:192] f32 (skip)
template<int K>
__global__ __launch_bounds__(256) void gemm_kernel(const short* __restrict__ A,
                                                   const short* __restrict__ Wcat,
                                                   const float* __restrict__ bcat,
                                                   float* __restrict__ qs,
                                                   __hip_bfloat16* __restrict__ kvb,
                                                   int M){
  constexpr int KP = K + 8;              // +16B pad: fragment reads alias only 2-way
  constexpr int UNITS = K / 8;           // 16B units per row
  __shared__ __attribute__((aligned(16))) short As[128 * KP];
  __shared__ __attribute__((aligned(16))) short Bs[128 * KP];
  const int tid = threadIdx.x;
  const int rt = blockIdx.x * 128, ct = blockIdx.y * 128;

  #pragma unroll
  for (int it = 0; it < UNITS / 2; ++it){
    int li = it * 256 + tid;
    int row = li / UNITS, u = li % UNITS;
    int grow = min(rt + row, M - 1);
    *(v8s*)&As[row * KP + u * 8] = *(const v8s*)(A + (size_t)grow * K + u * 8);
    int gcol = ct + row;                 // < 384 always
    *(v8s*)&Bs[row * KP + u * 8] = *(const v8s*)(Wcat + (size_t)gcol * K + u * 8);
  }
  __syncthreads();

  const int lane = tid & 63;
  const int wid  = tid >> 6;
  const int wm = wid >> 1, wn = wid & 1;
  const int fr = lane & 15, fk = lane >> 4;

  v4f acc[4][4];
  #pragma unroll
  for (int i = 0; i < 4; i++)
    #pragma unroll
    for (int j = 0; j < 4; j++) acc[i][j] = (v4f){0.f, 0.f, 0.f, 0.f};

  #pragma unroll
  for (int ks = 0; ks < K / 32; ++ks){
    const int kofs = ks * 32 + fk * 8;
    v8s a[4], b[4];
    #pragma unroll
    for (int i = 0; i < 4; i++)
      a[i] = *(const v8s*)&As[(wm * 64 + i * 16 + fr) * KP + kofs];
    #pragma unroll
    for (int j = 0; j < 4; j++)
      b[j] = *(const v8s*)&Bs[(wn * 64 + j * 16 + fr) * KP + kofs];
    #pragma unroll
    for (int i = 0; i < 4; i++)
      #pragma unroll
      for (int j = 0; j < 4; j++)
        acc[i][j] = __builtin_amdgcn_mfma_f32_16x16x32_bf16(a[i], b[j], acc[i][j], 0, 0, 0);
  }

  #pragma unroll
  for (int i = 0; i < 4; i++){
    #pragma unroll
    for (int j = 0; j < 4; j++){
      const int gcol = ct + wn * 64 + j * 16 + fr;
      const float bias = bcat[gcol];
      #pragma unroll
      for (int r = 0; r < 4; r++){
        const int grow = rt + wm * 64 + i * 16 + fk * 4 + r;
        if (grow < M){
          float val = acc[i][j][r] + bias;
          if (gcol < 96)       qs[(size_t)grow * 192 + gcol] = val;
          else if (gcol < 192) kvb[(size_t)grow * 192 + (gcol - 96)] = __float2bfloat16(val);
          else if (gcol < 288) kvb[(size_t)grow * 192 + 96 + (gcol - 192)] = __float2bfloat16(val);
          else                 qs[(size_t)grow * 192 + 96 + (gcol - 288)] = val;
        }
      }
    }
  }
}

// one wave per node; chunk of 16 edges.
// alpha role: lane = 4*g + h -> edge g (0..15), head h (0..3); 4-lane group reads one
//   coalesced 192B bf16 k-row. per-head softmax reductions via shfl_xor {4,8,16,32}.
// V role: lane = 16*vg + l -> edge residue vg (mod 4), features 6l..6l+5 (head l>>2);
//   16-lane group reads one coalesced 192B bf16 v-row. e/src moved via __shfl (no LDS).
// mode 0: gate + exact GELU -> bf16 h1b ; mode 1: gate + LayerNorm -> f32 outp
__global__ __launch_bounds__(256) void attn_kernel(
    const float* __restrict__ qs, const __hip_bfloat16* __restrict__ kv,
    const int* __restrict__ row_ptr, const int* __restrict__ col_src,
    const float* __restrict__ Wb, const float* __restrict__ gamma,
    const float* __restrict__ beta, float* __restrict__ outp,
    short* __restrict__ h1b, int mode){
  const int lane = threadIdx.x & 63;
  const int wid  = threadIdx.x >> 6;
  const int n = blockIdx.x * 4 + wid;
  if (n >= NN) return;
  const int h_a = lane & 3;
  const int g_a = lane >> 2;
  const int l_v = lane & 15;
  const int vg  = lane >> 4;
  const int h_v = l_v >> 2;

  float qr[24];
  {
    const float* qrow = qs + (size_t)n * 192 + h_a * 24;
    #pragma unroll
    for (int i = 0; i < 6; i++){
      float4 t = *(const float4*)(qrow + 4 * i);
      qr[4*i+0] = t.x; qr[4*i+1] = t.y; qr[4*i+2] = t.z; qr[4*i+3] = t.w;
    }
  }
  const int rs = row_ptr[n], re = row_ptr[n + 1];
  float m = -INFINITY, s = 0.f;
  float acc[6] = {0.f, 0.f, 0.f, 0.f, 0.f, 0.f};

  for (int cb = rs; cb < re; cb += 16){
    const int cn = re - cb;             // >=1
    bool act = g_a < cn;
    int srcv = 0;
    float al = -INFINITY;
    if (act){
      srcv = col_src[cb + g_a];
      const uint4* kp = (const uint4*)((const char*)kv + (size_t)srcv * 384 + h_a * 48);
      float dot = 0.f;
      #pragma unroll
      for (int w = 0; w < 3; w++){
        uint4 u = kp[w];
        dot = fmaf(qr[w*8+0], bl16(u.x), dot); dot = fmaf(qr[w*8+1], bh16(u.x), dot);
        dot = fmaf(qr[w*8+2], bl16(u.y), dot); dot = fmaf(qr[w*8+3], bh16(u.y), dot);
        dot = fmaf(qr[w*8+4], bl16(u.z), dot); dot = fmaf(qr[w*8+5], bh16(u.z), dot);
        dot = fmaf(qr[w*8+6], bl16(u.w), dot); dot = fmaf(qr[w*8+7], bh16(u.w), dot);
      }
      al = dot * 0.2041241452319315f;
    }
    float cm = al;
    cm = fmaxf(cm, __shfl_xor(cm, 4));
    cm = fmaxf(cm, __shfl_xor(cm, 8));
    cm = fmaxf(cm, __shfl_xor(cm, 16));
    cm = fmaxf(cm, __shfl_xor(cm, 32));
    float nm = fmaxf(m, cm);
    float r  = __expf(m - nm);
    float e  = __expf(al - nm);
    float cs = e;
    cs += __shfl_xor(cs, 4);
    cs += __shfl_xor(cs, 8);
    cs += __shfl_xor(cs, 16);
    cs += __shfl_xor(cs, 32);
    s = s * r + cs;
    m = nm;
    float rv = __shfl(r, h_v);
    #pragma unroll
    for (int i = 0; i < 6; i++) acc[i] *= rv;
    #pragma unroll
    for (int st = 0; st < 4; st++){
      int eidx = st * 4 + vg;
      int sl = 4 * eidx + h_v;
      float w  = __shfl(e, sl);
      int   sb = __shfl(srcv, sl);
      if (eidx < cn){
        const unsigned int* vp =
          (const unsigned int*)((const char*)kv + (size_t)sb * 384 + 192 + 12 * l_v);
        unsigned int u0 = vp[0], u1 = vp[1], u2 = vp[2];
        acc[0] = fmaf(w, bl16(u0), acc[0]); acc[1] = fmaf(w, bh16(u0), acc[1]);
        acc[2] = fmaf(w, bl16(u1), acc[2]); acc[3] = fmaf(w, bh16(u1), acc[3]);
        acc[4] = fmaf(w, bl16(u2), acc[4]); acc[5] = fmaf(w, bh16(u2), acc[5]);
      }
    }
  }

  #pragma unroll
  for (int i = 0; i < 6; i++){
    acc[i] += __shfl_xor(acc[i], 16);
    acc[i] += __shfl_xor(acc[i], 32);
  }
  float sv  = __shfl(s, h_v);
  float inv = (re > rs) ? 1.0f / sv : 0.f;
  float o[6], xr[6];
  #pragma unroll
  for (int i = 0; i < 6; i++) o[i] = acc[i] * inv;
  const float* xrp = qs + (size_t)n * 192 + 96 + 6 * l_v;
  #pragma unroll
  for (int i = 0; i < 6; i++) xr[i] = xrp[i];

  float p = 0.f;
  #pragma unroll
  for (int i = 0; i < 6; i++){
    int f = 6 * l_v + i;
    p += Wb[f] * o[i] + Wb[96 + f] * xr[i] + Wb[192 + f] * (o[i] - xr[i]);
  }
  p += __shfl_xor(p, 1);
  p += __shfl_xor(p, 2);
  p += __shfl_xor(p, 4);
  p += __shfl_xor(p, 8);
  float g = 1.0f / (1.0f + __expf(-p));
  float y[6];
  #pragma unroll
  for (int i = 0; i < 6; i++) y[i] = g * xr[i] + (1.0f - g) * o[i];

  if (mode == 0){
    #pragma unroll
    for (int i = 0; i < 6; i++)
      y[i] = 0.5f * y[i] * (1.0f + erff(y[i] * 0.7071067811865475f));
    if (vg == 0){
      short* op = h1b + (size_t)n * 96 + 6 * l_v;
      #pragma unroll
      for (int i = 0; i < 6; i++) op[i] = f2b(y[i]);
    }
  } else {
    float ssum = y[0] + y[1] + y[2] + y[3] + y[4] + y[5];
    ssum += __shfl_xor(ssum, 1);
    ssum += __shfl_xor(ssum, 2);
    ssum += __shfl_xor(ssum, 4);
    ssum += __shfl_xor(ssum, 8);
    float mu = ssum * (1.0f / 96.0f);
    float vsum = 0.f;
    #pragma unroll
    for (int i = 0; i < 6; i++){ float d = y[i] - mu; vsum += d * d; }
    vsum += __shfl_xor(vsum, 1);
    vsum += __shfl_xor(vsum, 2);
    vsum += __shfl_xor(vsum, 4);
    vsum += __shfl_xor(vsum, 8);
    float invs = rsqrtf(vsum * (1.0f / 96.0f) + 1e-5f);
    if (vg == 0){
      float* op = outp + (size_t)n * 96 + 6 * l_v;
      #pragma unroll
      for (int i = 0; i < 6; i++){
        int f = 6 * l_v + i;
        op[i] = (y[i] - mu) * invs * gamma[f] + beta[f];
      }
    }
  }
}

extern "C" void kernel_launch(void* const* d_in, const int* in_sizes, int n_in,
                              void* d_out, int out_size, void* d_ws, size_t ws_size,
                              hipStream_t stream){
  const float* x    = (const float*)d_in[0];
  const int*   ei   = (const int*)d_in[1];
  const float* Wq1  = (const float*)d_in[2];
  const float* bq1  = (const float*)d_in[3];
  const float* Wk1  = (const float*)d_in[4];
  const float* bk1  = (const float*)d_in[5];
  const float* Wv1  = (const float*)d_in[6];
  const float* bv1  = (const float*)d_in[7];
  const float* Ws1  = (const float*)d_in[8];
  const float* bs1  = (const float*)d_in[9];
  const float* Wb1  = (const float*)d_in[10];
  const float* Wq2  = (const float*)d_in[11];
  const float* bq2  = (const float*)d_in[12];
  const float* Wk2  = (const float*)d_in[13];
  const float* bk2  = (const float*)d_in[14];
  const float* Wv2  = (const float*)d_in[15];
  const float* bv2  = (const float*)d_in[16];
  const float* Ws2  = (const float*)d_in[17];
  const float* bs2  = (const float*)d_in[18];
  const float* Wb2  = (const float*)d_in[19];
  const float* gamma = (const float*)d_in[20];
  const float* beta  = (const float*)d_in[21];
  float* out = (float*)d_out;

  char* ws = (char*)d_ws;
  size_t off = 0;
  auto take = [&](size_t b) -> void* {
    void* p = ws + off;
    off += (b + 255) & ~(size_t)255;
    return p;
  };
  float* qs            = (float*)take((size_t)NN * 192 * 4);
  __hip_bfloat16* kvb  = (__hip_bfloat16*)take((size_t)NN * 192 * 2);
  short* xh            = (short*)take((size_t)NN * 128 * 2);  // xb (L1 in) / h1b (L2 in) share
  short* Wcat          = (short*)take((size_t)384 * 128 * 2);
  float* bcat          = (float*)take(384 * 4);
  int* deg             = (int*)take((size_t)NN * 4);
  int* cursor          = (int*)take((size_t)NN * 4);
  int* row_ptr         = (int*)take((size_t)(NN + 1) * 4);
  int* col_src         = (int*)take((size_t)EE * 4);

  // CSR build (shared by both layers)
  zero_i32<<<(NN + 255) / 256, 256, 0, stream>>>(deg, NN);
  hist_kernel<<<(EE + 255) / 256, 256, 0, stream>>>(ei, deg);
  scan_kernel<<<1, 1024, 0, stream>>>(deg, row_ptr, cursor, NN);
  fill_kernel<<<(EE + 255) / 256, 256, 0, stream>>>(ei, cursor, col_src);

  dim3 gg((NN + 127) / 128, 3);
  // layer 1
  cast_kernel<<<(NN * 128 / 8 + 255) / 256, 256, 0, stream>>>(x, xh, NN * 128 / 8);
  pack_kernel<<<384, 128, 0, stream>>>(Wq1, bq1, Wk1, bk1, Wv1, bv1, Ws1, bs1, Wcat, bcat, 128);
  gemm_kernel<128><<<gg, 256, 0, stream>>>(xh, Wcat, bcat, qs, kvb, NN);
  attn_kernel<<<(NN + 3) / 4, 256, 0, stream>>>(qs, kvb, row_ptr, col_src, Wb1,
                                                nullptr, nullptr, nullptr, xh, 0);
  // layer 2
  pack_kernel<<<384, 128, 0, stream>>>(Wq2, bq2, Wk2, bk2, Wv2, bv2, Ws2, bs2, Wcat, bcat, 96);
  gemm_kernel<96><<<gg, 256, 0, stream>>>(xh, Wcat, bcat, qs, kvb, NN);
  attn_kernel<<<(NN + 3) / 4, 256, 0, stream>>>(qs, kvb, row_ptr, col_src, Wb2,
                                                gamma, beta, out, nullptr, 1);
}

// Round 4
// 306.134 us; speedup vs baseline: 2.0106x; 1.1714x over previous
//
#include <hip/hip_runtime.h>
#include <hip/hip_bf16.h>
#include <math.h>

constexpr int NN = 50000;
constexpr int EE = 800000;
constexpr int SCAN_NB = (NN + 255) / 256;   // 196

typedef short v8s __attribute__((ext_vector_type(8)));
typedef float v4f __attribute__((ext_vector_type(4)));

__device__ __forceinline__ float bl16(unsigned int u){ return __uint_as_float(u << 16); }
__device__ __forceinline__ float bh16(unsigned int u){ return __uint_as_float(u & 0xffff0000u); }
__device__ __forceinline__ short f2b(float f){
  __hip_bfloat16 h = __float2bfloat16(f);
  return *reinterpret_cast<short*>(&h);
}

__global__ void zero_i32(int* __restrict__ p, int n){
  int i = blockIdx.x * blockDim.x + threadIdx.x;
  if (i < n) p[i] = 0;
}

__global__ void hist_kernel(const int* __restrict__ ei, int* __restrict__ deg){
  int e = blockIdx.x * blockDim.x + threadIdx.x;
  if (e < EE) atomicAdd(&deg[ei[EE + e]], 1);
}

// --- 3-phase parallel exclusive scan of deg[NN] ---
__global__ __launch_bounds__(256) void partial_sum_kernel(const int* __restrict__ deg,
                                                          int* __restrict__ psum){
  int b = blockIdx.x, tid = threadIdx.x, lane = tid & 63, wv = tid >> 6;
  int i = b * 256 + tid;
  int v = (i < NN) ? deg[i] : 0;
  #pragma unroll
  for (int m = 1; m < 64; m <<= 1) v += __shfl_xor(v, m);
  __shared__ int ws[4];
  if (lane == 0) ws[wv] = v;
  __syncthreads();
  if (tid == 0) psum[b] = ws[0] + ws[1] + ws[2] + ws[3];
}

__global__ __launch_bounds__(256) void scan_partials_kernel(int* __restrict__ psum){
  int tid = threadIdx.x, lane = tid & 63, wv = tid >> 6;
  int own = (tid < SCAN_NB) ? psum[tid] : 0;
  int v = own;
  #pragma unroll
  for (int off = 1; off < 64; off <<= 1){
    int t = __shfl_up(v, off);
    if (lane >= off) v += t;
  }
  __shared__ int ws[4];
  if (lane == 63) ws[wv] = v;
  __syncthreads();
  int add = 0;
  #pragma unroll
  for (int w = 0; w < 4; w++) if (w < wv) add += ws[w];
  if (tid < SCAN_NB) psum[tid] = v + add - own;     // exclusive
}

__global__ __launch_bounds__(256) void final_scan_kernel(const int* __restrict__ deg,
                                                         const int* __restrict__ psum,
                                                         int* __restrict__ row_ptr,
                                                         int* __restrict__ cursor){
  int b = blockIdx.x, tid = threadIdx.x, lane = tid & 63, wv = tid >> 6;
  int i = b * 256 + tid;
  int d = (i < NN) ? deg[i] : 0;
  int v = d;
  #pragma unroll
  for (int off = 1; off < 64; off <<= 1){
    int t = __shfl_up(v, off);
    if (lane >= off) v += t;
  }
  __shared__ int ws[4];
  if (lane == 63) ws[wv] = v;
  __syncthreads();
  int add = psum[b];
  #pragma unroll
  for (int w = 0; w < 4; w++) if (w < wv) add += ws[w];
  if (i < NN){
    row_ptr[i + 1] = add + v;
    cursor[i]      = add + v - d;
  }
  if (i == 0) row_ptr[0] = 0;
}

__global__ void fill_kernel(const int* __restrict__ ei, int* __restrict__ cursor,
                            int* __restrict__ col_src){
  int e = blockIdx.x * blockDim.x + threadIdx.x;
  if (e < EE){
    int src = ei[e], dst = ei[EE + e];
    int pos = atomicAdd(&cursor[dst], 1);
    col_src[pos] = src;
  }
}

// pack 4 weight matrices (each [96][K] f32) + biases into bf16 Wcat[384][K], f32 bcat[384]
__global__ void pack_kernel(const float* __restrict__ Wq, const float* __restrict__ bq,
                            const float* __restrict__ Wk, const float* __restrict__ bk,
                            const float* __restrict__ Wv, const float* __restrict__ bv,
                            const float* __restrict__ Ws, const float* __restrict__ bs,
                            short* __restrict__ Wcat, float* __restrict__ bcat, int K){
  int c = blockIdx.x;            // 0..383
  int which = c / 96, r = c % 96;
  const float* Wsel = which == 0 ? Wq : which == 1 ? Wk : which == 2 ? Wv : Ws;
  const float* bsel = which == 0 ? bq : which == 1 ? bk : which == 2 ? bv : bs;
  for (int k = threadIdx.x; k < K; k += blockDim.x)
    Wcat[(size_t)c * K + k] = f2b(Wsel[(size_t)r * K + k]);
  if (threadIdx.x == 0) bcat[c] = bsel[r];
}

// C[M][384] = A[M][K] @ Wcat[384][K](bf16)^T + bcat, via mfma_f32_16x16x32_bf16.
// A is f32 (converted in staging) when AF32, else bf16. 128x128 tile, 4 waves 2x2.
template<int K, bool AF32>
__global__ __launch_bounds__(256) void gemm_kernel(const void* __restrict__ Ain,
                                                   const short* __restrict__ Wcat,
                                                   const float* __restrict__ bcat,
                                                   float* __restrict__ qs,
                                                   __hip_bfloat16* __restrict__ kvb,
                                                   int M){
  constexpr int KP = K + 8;              // +16B pad: fragment reads alias only 2-way
  constexpr int UNITS = K / 8;           // 8-elem units per row
  __shared__ __attribute__((aligned(16))) short As[128 * KP];
  __shared__ __attribute__((aligned(16))) short Bs[128 * KP];
  const int tid = threadIdx.x;
  const int rt = blockIdx.x * 128, ct = blockIdx.y * 128;

  #pragma unroll
  for (int it = 0; it < UNITS / 2; ++it){
    int li = it * 256 + tid;
    int row = li / UNITS, u = li % UNITS;
    int grow = min(rt + row, M - 1);
    if constexpr (AF32){
      const float* A = (const float*)Ain;
      float4 a0 = *(const float4*)(A + (size_t)grow * K + u * 8);
      float4 a1 = *(const float4*)(A + (size_t)grow * K + u * 8 + 4);
      v8s o;
      o[0] = f2b(a0.x); o[1] = f2b(a0.y); o[2] = f2b(a0.z); o[3] = f2b(a0.w);
      o[4] = f2b(a1.x); o[5] = f2b(a1.y); o[6] = f2b(a1.z); o[7] = f2b(a1.w);
      *(v8s*)&As[row * KP + u * 8] = o;
    } else {
      const short* A = (const short*)Ain;
      *(v8s*)&As[row * KP + u * 8] = *(const v8s*)(A + (size_t)grow * K + u * 8);
    }
    int gcol = ct + row;                 // < 384 always
    *(v8s*)&Bs[row * KP + u * 8] = *(const v8s*)(Wcat + (size_t)gcol * K + u * 8);
  }
  __syncthreads();

  const int lane = tid & 63;
  const int wid  = tid >> 6;
  const int wm = wid >> 1, wn = wid & 1;
  const int fr = lane & 15, fk = lane >> 4;

  v4f acc[4][4];
  #pragma unroll
  for (int i = 0; i < 4; i++)
    #pragma unroll
    for (int j = 0; j < 4; j++) acc[i][j] = (v4f){0.f, 0.f, 0.f, 0.f};

  #pragma unroll
  for (int ks = 0; ks < K / 32; ++ks){
    const int kofs = ks * 32 + fk * 8;
    v8s a[4], b[4];
    #pragma unroll
    for (int i = 0; i < 4; i++)
      a[i] = *(const v8s*)&As[(wm * 64 + i * 16 + fr) * KP + kofs];
    #pragma unroll
    for (int j = 0; j < 4; j++)
      b[j] = *(const v8s*)&Bs[(wn * 64 + j * 16 + fr) * KP + kofs];
    #pragma unroll
    for (int i = 0; i < 4; i++)
      #pragma unroll
      for (int j = 0; j < 4; j++)
        acc[i][j] = __builtin_amdgcn_mfma_f32_16x16x32_bf16(a[i], b[j], acc[i][j], 0, 0, 0);
  }

  #pragma unroll
  for (int i = 0; i < 4; i++){
    #pragma unroll
    for (int j = 0; j < 4; j++){
      const int gcol = ct + wn * 64 + j * 16 + fr;
      const float bias = bcat[gcol];
      #pragma unroll
      for (int r = 0; r < 4; r++){
        const int grow = rt + wm * 64 + i * 16 + fk * 4 + r;
        if (grow < M){
          float val = acc[i][j][r] + bias;
          if (gcol < 96)       qs[(size_t)grow * 192 + gcol] = val;
          else if (gcol < 192) kvb[(size_t)grow * 192 + (gcol - 96)] = __float2bfloat16(val);
          else if (gcol < 288) kvb[(size_t)grow * 192 + 96 + (gcol - 192)] = __float2bfloat16(val);
          else                 qs[(size_t)grow * 192 + 96 + (gcol - 288)] = val;
        }
      }
    }
  }
}

// one wave per node; chunk of 16 edges.
// alpha role: lane = 4*g + h -> edge g, head h; 4-lane group reads one 192B bf16 k-row.
// V role: lane = 16*vg + l -> edges st*4+vg, features 6l..6l+5; v-rows PREFETCHED into
//   registers concurrently with the k-gather (clamped indices, masked weights).
__global__ __launch_bounds__(256) void attn_kernel(
    const float* __restrict__ qs, const __hip_bfloat16* __restrict__ kv,
    const int* __restrict__ row_ptr, const int* __restrict__ col_src,
    const float* __restrict__ Wb, const float* __restrict__ gamma,
    const float* __restrict__ beta, float* __restrict__ outp,
    short* __restrict__ h1b, int mode){
  const int lane = threadIdx.x & 63;
  const int wid  = threadIdx.x >> 6;
  const int n = blockIdx.x * 4 + wid;
  if (n >= NN) return;
  const int h_a = lane & 3;
  const int g_a = lane >> 2;
  const int l_v = lane & 15;
  const int vg  = lane >> 4;
  const int h_v = l_v >> 2;

  float qr[24];
  {
    const float* qrow = qs + (size_t)n * 192 + h_a * 24;
    #pragma unroll
    for (int i = 0; i < 6; i++){
      float4 t = *(const float4*)(qrow + 4 * i);
      qr[4*i+0] = t.x; qr[4*i+1] = t.y; qr[4*i+2] = t.z; qr[4*i+3] = t.w;
    }
  }
  const int rs = row_ptr[n], re = row_ptr[n + 1];
  float m = -INFINITY, s = 0.f;
  float acc[6] = {0.f, 0.f, 0.f, 0.f, 0.f, 0.f};

  for (int cb = rs; cb < re; cb += 16){
    const int cn = re - cb;             // >=1
    // alpha-role src (clamped; masked later)
    int srcv = col_src[cb + min(g_a, cn - 1)];
    // V-role: prefetch v-rows into registers (independent of alpha chain)
    unsigned int vd[4][3];
    #pragma unroll
    for (int st = 0; st < 4; st++){
      int eidx = min(st * 4 + vg, cn - 1);
      int sb = col_src[cb + eidx];
      const unsigned int* vp =
        (const unsigned int*)((const char*)kv + (size_t)sb * 384 + 192 + 12 * l_v);
      vd[st][0] = vp[0]; vd[st][1] = vp[1]; vd[st][2] = vp[2];
    }
    // k gather + dot
    const uint4* kp = (const uint4*)((const char*)kv + (size_t)srcv * 384 + h_a * 48);
    float dot = 0.f;
    #pragma unroll
    for (int w = 0; w < 3; w++){
      uint4 u = kp[w];
      dot = fmaf(qr[w*8+0], bl16(u.x), dot); dot = fmaf(qr[w*8+1], bh16(u.x), dot);
      dot = fmaf(qr[w*8+2], bl16(u.y), dot); dot = fmaf(qr[w*8+3], bh16(u.y), dot);
      dot = fmaf(qr[w*8+4], bl16(u.z), dot); dot = fmaf(qr[w*8+5], bh16(u.z), dot);
      dot = fmaf(qr[w*8+6], bl16(u.w), dot); dot = fmaf(qr[w*8+7], bh16(u.w), dot);
    }
    float al = (g_a < cn) ? dot * 0.2041241452319315f : -INFINITY;
    float cm = al;
    cm = fmaxf(cm, __shfl_xor(cm, 4));
    cm = fmaxf(cm, __shfl_xor(cm, 8));
    cm = fmaxf(cm, __shfl_xor(cm, 16));
    cm = fmaxf(cm, __shfl_xor(cm, 32));
    float nm = fmaxf(m, cm);
    float r  = __expf(m - nm);
    float e  = __expf(al - nm);
    float cs = e;
    cs += __shfl_xor(cs, 4);
    cs += __shfl_xor(cs, 8);
    cs += __shfl_xor(cs, 16);
    cs += __shfl_xor(cs, 32);
    s = s * r + cs;
    m = nm;
    // apply weights to prefetched v
    float rv = __shfl(r, h_v);
    #pragma unroll
    for (int i = 0; i < 6; i++) acc[i] *= rv;
    #pragma unroll
    for (int st = 0; st < 4; st++){
      int eidx = st * 4 + vg;
      float w = __shfl(e, 4 * min(eidx, cn - 1) + h_v);
      if (eidx >= cn) w = 0.f;
      unsigned int u0 = vd[st][0], u1 = vd[st][1], u2 = vd[st][2];
      acc[0] = fmaf(w, bl16(u0), acc[0]); acc[1] = fmaf(w, bh16(u0), acc[1]);
      acc[2] = fmaf(w, bl16(u1), acc[2]); acc[3] = fmaf(w, bh16(u1), acc[3]);
      acc[4] = fmaf(w, bl16(u2), acc[4]); acc[5] = fmaf(w, bh16(u2), acc[5]);
    }
  }

  #pragma unroll
  for (int i = 0; i < 6; i++){
    acc[i] += __shfl_xor(acc[i], 16);
    acc[i] += __shfl_xor(acc[i], 32);
  }
  float sv  = __shfl(s, h_v);
  float inv = (re > rs) ? 1.0f / sv : 0.f;
  float o[6], xr[6];
  #pragma unroll
  for (int i = 0; i < 6; i++) o[i] = acc[i] * inv;
  const float* xrp = qs + (size_t)n * 192 + 96 + 6 * l_v;
  #pragma unroll
  for (int i = 0; i < 6; i++) xr[i] = xrp[i];

  float p = 0.f;
  #pragma unroll
  for (int i = 0; i < 6; i++){
    int f = 6 * l_v + i;
    p += Wb[f] * o[i] + Wb[96 + f] * xr[i] + Wb[192 + f] * (o[i] - xr[i]);
  }
  p += __shfl_xor(p, 1);
  p += __shfl_xor(p, 2);
  p += __shfl_xor(p, 4);
  p += __shfl_xor(p, 8);
  float g = 1.0f / (1.0f + __expf(-p));
  float y[6];
  #pragma unroll
  for (int i = 0; i < 6; i++) y[i] = g * xr[i] + (1.0f - g) * o[i];

  if (mode == 0){
    #pragma unroll
    for (int i = 0; i < 6; i++)
      y[i] = 0.5f * y[i] * (1.0f + erff(y[i] * 0.7071067811865475f));
    if (vg == 0){
      short* op = h1b + (size_t)n * 96 + 6 * l_v;
      #pragma unroll
      for (int i = 0; i < 6; i++) op[i] = f2b(y[i]);
    }
  } else {
    float ssum = y[0] + y[1] + y[2] + y[3] + y[4] + y[5];
    ssum += __shfl_xor(ssum, 1);
    ssum += __shfl_xor(ssum, 2);
    ssum += __shfl_xor(ssum, 4);
    ssum += __shfl_xor(ssum, 8);
    float mu = ssum * (1.0f / 96.0f);
    float vsum = 0.f;
    #pragma unroll
    for (int i = 0; i < 6; i++){ float d = y[i] - mu; vsum += d * d; }
    vsum += __shfl_xor(vsum, 1);
    vsum += __shfl_xor(vsum, 2);
    vsum += __shfl_xor(vsum, 4);
    vsum += __shfl_xor(vsum, 8);
    float invs = rsqrtf(vsum * (1.0f / 96.0f) + 1e-5f);
    if (vg == 0){
      float* op = outp + (size_t)n * 96 + 6 * l_v;
      #pragma unroll
      for (int i = 0; i < 6; i++){
        int f = 6 * l_v + i;
        op[i] = (y[i] - mu) * invs * gamma[f] + beta[f];
      }
    }
  }
}

extern "C" void kernel_launch(void* const* d_in, const int* in_sizes, int n_in,
                              void* d_out, int out_size, void* d_ws, size_t ws_size,
                              hipStream_t stream){
  const float* x    = (const float*)d_in[0];
  const int*   ei   = (const int*)d_in[1];
  const float* Wq1  = (const float*)d_in[2];
  const float* bq1  = (const float*)d_in[3];
  const float* Wk1  = (const float*)d_in[4];
  const float* bk1  = (const float*)d_in[5];
  const float* Wv1  = (const float*)d_in[6];
  const float* bv1  = (const float*)d_in[7];
  const float* Ws1  = (const float*)d_in[8];
  const float* bs1  = (const float*)d_in[9];
  const float* Wb1  = (const float*)d_in[10];
  const float* Wq2  = (const float*)d_in[11];
  const float* bq2  = (const float*)d_in[12];
  const float* Wk2  = (const float*)d_in[13];
  const float* bk2  = (const float*)d_in[14];
  const float* Wv2  = (const float*)d_in[15];
  const float* bv2  = (const float*)d_in[16];
  const float* Ws2  = (const float*)d_in[17];
  const float* bs2  = (const float*)d_in[18];
  const float* Wb2  = (const float*)d_in[19];
  const float* gamma = (const float*)d_in[20];
  const float* beta  = (const float*)d_in[21];
  float* out = (float*)d_out;

  char* ws = (char*)d_ws;
  size_t off = 0;
  auto take = [&](size_t b) -> void* {
    void* p = ws + off;
    off += (b + 255) & ~(size_t)255;
    return p;
  };
  float* qs            = (float*)take((size_t)NN * 192 * 4);
  __hip_bfloat16* kvb  = (__hip_bfloat16*)take((size_t)NN * 192 * 2);
  short* h1b           = (short*)take((size_t)NN * 96 * 2);
  short* Wcat          = (short*)take((size_t)384 * 128 * 2);
  float* bcat          = (float*)take(384 * 4);
  int* deg             = (int*)take((size_t)NN * 4);
  int* cursor          = (int*)take((size_t)NN * 4);
  int* row_ptr         = (int*)take((size_t)(NN + 1) * 4);
  int* col_src         = (int*)take((size_t)EE * 4);
  int* psum            = (int*)take((size_t)SCAN_NB * 4);

  // CSR build (shared by both layers)
  zero_i32<<<(NN + 255) / 256, 256, 0, stream>>>(deg, NN);
  hist_kernel<<<(EE + 255) / 256, 256, 0, stream>>>(ei, deg);
  partial_sum_kernel<<<SCAN_NB, 256, 0, stream>>>(deg, psum);
  scan_partials_kernel<<<1, 256, 0, stream>>>(psum);
  final_scan_kernel<<<SCAN_NB, 256, 0, stream>>>(deg, psum, row_ptr, cursor);
  fill_kernel<<<(EE + 255) / 256, 256, 0, stream>>>(ei, cursor, col_src);

  dim3 gg((NN + 127) / 128, 3);
  // layer 1 (A = x f32, converted in gemm staging)
  pack_kernel<<<384, 128, 0, stream>>>(Wq1, bq1, Wk1, bk1, Wv1, bv1, Ws1, bs1, Wcat, bcat, 128);
  gemm_kernel<128, true><<<gg, 256, 0, stream>>>(x, Wcat, bcat, qs, kvb, NN);
  attn_kernel<<<(NN + 3) / 4, 256, 0, stream>>>(qs, kvb, row_ptr, col_src, Wb1,
                                                nullptr, nullptr, nullptr, h1b, 0);
  // layer 2 (A = h1b bf16)
  pack_kernel<<<384, 128, 0, stream>>>(Wq2, bq2, Wk2, bk2, Wv2, bv2, Ws2, bs2, Wcat, bcat, 96);
  gemm_kernel<96, false><<<gg, 256, 0, stream>>>(h1b, Wcat, bcat, qs, kvb, NN);
  attn_kernel<<<(NN + 3) / 4, 256, 0, stream>>>(qs, kvb, row_ptr, col_src, Wb2,
                                                gamma, beta, out, nullptr, 1);
}

// Round 5
// 294.220 us; speedup vs baseline: 2.0921x; 1.0405x over previous
//
#include <hip/hip_runtime.h>
#include <hip/hip_bf16.h>
#include <hip/hip_fp16.h>
#include <math.h>

constexpr int NN = 50000;
constexpr int EE = 800000;
constexpr int SCAN_NB = (NN + 255) / 256;   // 196

typedef short v8s __attribute__((ext_vector_type(8)));
typedef float v4f __attribute__((ext_vector_type(4)));

__device__ __forceinline__ short f2b(float f){
  __hip_bfloat16 h = __float2bfloat16(f);
  return *reinterpret_cast<short*>(&h);
}
__device__ __forceinline__ __half2 u2h2(unsigned int u){
  union { unsigned int u; __half2 h; } c; c.u = u; return c.h;
}

__global__ void zero_i32(int* __restrict__ p, int n){
  int i = blockIdx.x * blockDim.x + threadIdx.x;
  if (i < n) p[i] = 0;
}

__global__ void hist_kernel(const int* __restrict__ ei, int* __restrict__ deg){
  int e = blockIdx.x * blockDim.x + threadIdx.x;
  if (e < EE) atomicAdd(&deg[ei[EE + e]], 1);
}

// --- 3-phase parallel exclusive scan of deg[NN] ---
__global__ __launch_bounds__(256) void partial_sum_kernel(const int* __restrict__ deg,
                                                          int* __restrict__ psum){
  int b = blockIdx.x, tid = threadIdx.x, lane = tid & 63, wv = tid >> 6;
  int i = b * 256 + tid;
  int v = (i < NN) ? deg[i] : 0;
  #pragma unroll
  for (int m = 1; m < 64; m <<= 1) v += __shfl_xor(v, m);
  __shared__ int ws[4];
  if (lane == 0) ws[wv] = v;
  __syncthreads();
  if (tid == 0) psum[b] = ws[0] + ws[1] + ws[2] + ws[3];
}

__global__ __launch_bounds__(256) void scan_partials_kernel(int* __restrict__ psum){
  int tid = threadIdx.x, lane = tid & 63, wv = tid >> 6;
  int own = (tid < SCAN_NB) ? psum[tid] : 0;
  int v = own;
  #pragma unroll
  for (int off = 1; off < 64; off <<= 1){
    int t = __shfl_up(v, off);
    if (lane >= off) v += t;
  }
  __shared__ int ws[4];
  if (lane == 63) ws[wv] = v;
  __syncthreads();
  int add = 0;
  #pragma unroll
  for (int w = 0; w < 4; w++) if (w < wv) add += ws[w];
  if (tid < SCAN_NB) psum[tid] = v + add - own;     // exclusive
}

__global__ __launch_bounds__(256) void final_scan_kernel(const int* __restrict__ deg,
                                                         const int* __restrict__ psum,
                                                         int* __restrict__ row_ptr,
                                                         int* __restrict__ cursor){
  int b = blockIdx.x, tid = threadIdx.x, lane = tid & 63, wv = tid >> 6;
  int i = b * 256 + tid;
  int d = (i < NN) ? deg[i] : 0;
  int v = d;
  #pragma unroll
  for (int off = 1; off < 64; off <<= 1){
    int t = __shfl_up(v, off);
    if (lane >= off) v += t;
  }
  __shared__ int ws[4];
  if (lane == 63) ws[wv] = v;
  __syncthreads();
  int add = psum[b];
  #pragma unroll
  for (int w = 0; w < 4; w++) if (w < wv) add += ws[w];
  if (i < NN){
    row_ptr[i + 1] = add + v;
    cursor[i]      = add + v - d;
  }
  if (i == 0) row_ptr[0] = 0;
}

__global__ void fill_kernel(const int* __restrict__ ei, int* __restrict__ cursor,
                            int* __restrict__ col_src){
  int e = blockIdx.x * blockDim.x + threadIdx.x;
  if (e < EE){
    int src = ei[e], dst = ei[EE + e];
    int pos = atomicAdd(&cursor[dst], 1);
    col_src[pos] = src;
  }
}

// pack 4 weight matrices (each [96][K] f32) + biases into bf16 Wcat[384][K], f32 bcat[384]
__global__ void pack_kernel(const float* __restrict__ Wq, const float* __restrict__ bq,
                            const float* __restrict__ Wk, const float* __restrict__ bk,
                            const float* __restrict__ Wv, const float* __restrict__ bv,
                            const float* __restrict__ Ws, const float* __restrict__ bs,
                            short* __restrict__ Wcat, float* __restrict__ bcat, int K){
  int c = blockIdx.x;            // 0..383
  int which = c / 96, r = c % 96;
  const float* Wsel = which == 0 ? Wq : which == 1 ? Wk : which == 2 ? Wv : Ws;
  const float* bsel = which == 0 ? bq : which == 1 ? bk : which == 2 ? bv : bs;
  for (int k = threadIdx.x; k < K; k += blockDim.x)
    Wcat[(size_t)c * K + k] = f2b(Wsel[(size_t)r * K + k]);
  if (threadIdx.x == 0) bcat[c] = bsel[r];
}

// C[M][384] = A[M][K] @ Wcat[384][K](bf16)^T + bcat, via mfma_f32_16x16x32_bf16.
// 256x128 tile, 8 waves 4x2 (512 thr). Whole K staged in LDS once.
// Epilogue: cols 0-95 -> qs f32 (q); 96-191 -> kv f16 (k); 192-287 -> kv f16 (v);
// 288-383 -> qs f32 (skip)
template<int K, bool AF32>
__global__ __launch_bounds__(512) void gemm_kernel(const void* __restrict__ Ain,
                                                   const short* __restrict__ Wcat,
                                                   const float* __restrict__ bcat,
                                                   float* __restrict__ qs,
                                                   __half* __restrict__ kvb,
                                                   int M){
  constexpr int KP = K + 8;              // +16B pad: fragment reads alias only 2-way
  constexpr int UNITS = K / 8;           // 8-elem units per row
  __shared__ __attribute__((aligned(16))) short As[256 * KP];
  __shared__ __attribute__((aligned(16))) short Bs[128 * KP];
  const int tid = threadIdx.x;
  const int rt = blockIdx.x * 256, ct = blockIdx.y * 128;

  #pragma unroll
  for (int it = 0; it < (256 * UNITS) / 512; ++it){
    int li = it * 512 + tid;
    int row = li / UNITS, u = li % UNITS;
    int grow = min(rt + row, M - 1);
    if constexpr (AF32){
      const float* A = (const float*)Ain;
      float4 a0 = *(const float4*)(A + (size_t)grow * K + u * 8);
      float4 a1 = *(const float4*)(A + (size_t)grow * K + u * 8 + 4);
      v8s o;
      o[0] = f2b(a0.x); o[1] = f2b(a0.y); o[2] = f2b(a0.z); o[3] = f2b(a0.w);
      o[4] = f2b(a1.x); o[5] = f2b(a1.y); o[6] = f2b(a1.z); o[7] = f2b(a1.w);
      *(v8s*)&As[row * KP + u * 8] = o;
    } else {
      const short* A = (const short*)Ain;
      *(v8s*)&As[row * KP + u * 8] = *(const v8s*)(A + (size_t)grow * K + u * 8);
    }
  }
  #pragma unroll
  for (int it = 0; it < (128 * UNITS) / 512; ++it){
    int li = it * 512 + tid;
    int row = li / UNITS, u = li % UNITS;
    int gcol = ct + row;                 // < 384 always
    *(v8s*)&Bs[row * KP + u * 8] = *(const v8s*)(Wcat + (size_t)gcol * K + u * 8);
  }
  __syncthreads();

  const int lane = tid & 63;
  const int wid  = tid >> 6;
  const int wm = wid >> 1, wn = wid & 1;
  const int fr = lane & 15, fk = lane >> 4;

  v4f acc[4][4];
  #pragma unroll
  for (int i = 0; i < 4; i++)
    #pragma unroll
    for (int j = 0; j < 4; j++) acc[i][j] = (v4f){0.f, 0.f, 0.f, 0.f};

  #pragma unroll
  for (int ks = 0; ks < K / 32; ++ks){
    const int kofs = ks * 32 + fk * 8;
    v8s a[4], b[4];
    #pragma unroll
    for (int i = 0; i < 4; i++)
      a[i] = *(const v8s*)&As[(wm * 64 + i * 16 + fr) * KP + kofs];
    #pragma unroll
    for (int j = 0; j < 4; j++)
      b[j] = *(const v8s*)&Bs[(wn * 64 + j * 16 + fr) * KP + kofs];
    #pragma unroll
    for (int i = 0; i < 4; i++)
      #pragma unroll
      for (int j = 0; j < 4; j++)
        acc[i][j] = __builtin_amdgcn_mfma_f32_16x16x32_bf16(a[i], b[j], acc[i][j], 0, 0, 0);
  }

  #pragma unroll
  for (int i = 0; i < 4; i++){
    #pragma unroll
    for (int j = 0; j < 4; j++){
      const int gcol = ct + wn * 64 + j * 16 + fr;
      const float bias = bcat[gcol];
      #pragma unroll
      for (int r = 0; r < 4; r++){
        const int grow = rt + wm * 64 + i * 16 + fk * 4 + r;
        if (grow < M){
          float val = acc[i][j][r] + bias;
          if (gcol < 96)       qs[(size_t)grow * 192 + gcol] = val;
          else if (gcol < 192) kvb[(size_t)grow * 192 + (gcol - 96)] = __float2half(val);
          else if (gcol < 288) kvb[(size_t)grow * 192 + 96 + (gcol - 192)] = __float2half(val);
          else                 qs[(size_t)grow * 192 + 96 + (gcol - 288)] = val;
        }
      }
    }
  }
}

// one wave per node; chunk of 16 edges. kv rows are f16 (k[0:96], v[96:192]).
// alpha role: lane = 4*g + h -> edge g, head h; 4-lane group reads one 192B k-row;
//   q.k dot via packed __hfma2 (v_pk_fma_f16). V role: lane = 16*vg + l -> edges
//   st*4+vg, features 6l..6l+5; srcs via __shfl from alpha lanes; v prefetched to regs;
//   per-chunk accumulation in half2, folded into f32 acc with fused rescale.
__global__ __launch_bounds__(256) void attn_kernel(
    const float* __restrict__ qs, const __half* __restrict__ kv,
    const int* __restrict__ row_ptr, const int* __restrict__ col_src,
    const float* __restrict__ Wb, const float* __restrict__ gamma,
    const float* __restrict__ beta, float* __restrict__ outp,
    short* __restrict__ h1b, int mode){
  const int lane = threadIdx.x & 63;
  const int wid  = threadIdx.x >> 6;
  const int n = blockIdx.x * 4 + wid;
  if (n >= NN) return;
  const int h_a = lane & 3;
  const int g_a = lane >> 2;
  const int l_v = lane & 15;
  const int vg  = lane >> 4;
  const int h_v = l_v >> 2;

  // q for head h_a packed into 12 half2
  __half2 qh[12];
  {
    const float* qrow = qs + (size_t)n * 192 + h_a * 24;
    #pragma unroll
    for (int i = 0; i < 12; i++)
      qh[i] = __floats2half2_rn(qrow[2 * i], qrow[2 * i + 1]);
  }
  const int rs = row_ptr[n], re = row_ptr[n + 1];
  float m = -INFINITY, s = 0.f;
  float acc[6] = {0.f, 0.f, 0.f, 0.f, 0.f, 0.f};

  for (int cb = rs; cb < re; cb += 16){
    const int cn = re - cb;             // >=1
    int srcv = col_src[cb + min(g_a, cn - 1)];
    // v-role srcs via shfl from alpha lanes (lane 4*eidx holds col_src[cb+eidx])
    int sb[4];
    #pragma unroll
    for (int st = 0; st < 4; st++)
      sb[st] = __shfl(srcv, 4 * min(st * 4 + vg, cn - 1));
    // prefetch v rows (independent of alpha chain)
    unsigned int vd[4][3];
    #pragma unroll
    for (int st = 0; st < 4; st++){
      const unsigned int* vp =
        (const unsigned int*)((const char*)kv + (size_t)sb[st] * 384 + 192 + 12 * l_v);
      vd[st][0] = vp[0]; vd[st][1] = vp[1]; vd[st][2] = vp[2];
    }
    // k gather + packed dot
    const uint4* kp = (const uint4*)((const char*)kv + (size_t)srcv * 384 + h_a * 48);
    uint4 u0 = kp[0], u1 = kp[1], u2 = kp[2];
    __half2 d0 = __floats2half2_rn(0.f, 0.f), d1 = d0;
    d0 = __hfma2(qh[0],  u2h2(u0.x), d0); d1 = __hfma2(qh[1],  u2h2(u0.y), d1);
    d0 = __hfma2(qh[2],  u2h2(u0.z), d0); d1 = __hfma2(qh[3],  u2h2(u0.w), d1);
    d0 = __hfma2(qh[4],  u2h2(u1.x), d0); d1 = __hfma2(qh[5],  u2h2(u1.y), d1);
    d0 = __hfma2(qh[6],  u2h2(u1.z), d0); d1 = __hfma2(qh[7],  u2h2(u1.w), d1);
    d0 = __hfma2(qh[8],  u2h2(u2.x), d0); d1 = __hfma2(qh[9],  u2h2(u2.y), d1);
    d0 = __hfma2(qh[10], u2h2(u2.z), d0); d1 = __hfma2(qh[11], u2h2(u2.w), d1);
    float dot = __low2float(d0) + __high2float(d0) + __low2float(d1) + __high2float(d1);
    float al = (g_a < cn) ? dot * 0.2041241452319315f : -INFINITY;

    float cm = al;
    cm = fmaxf(cm, __shfl_xor(cm, 4));
    cm = fmaxf(cm, __shfl_xor(cm, 8));
    cm = fmaxf(cm, __shfl_xor(cm, 16));
    cm = fmaxf(cm, __shfl_xor(cm, 32));
    float nm = fmaxf(m, cm);
    float r  = __expf(m - nm);          // first chunk: 0
    float e  = __expf(al - nm);         // padded lanes: 0
    float cs = e;
    cs += __shfl_xor(cs, 4);
    cs += __shfl_xor(cs, 8);
    cs += __shfl_xor(cs, 16);
    cs += __shfl_xor(cs, 32);
    s = s * r + cs;
    m = nm;

    // per-chunk half2 accumulation of weighted v
    float rv = __shfl(r, h_v);
    __half2 ch0 = __floats2half2_rn(0.f, 0.f), ch1 = ch0, ch2 = ch0;
    #pragma unroll
    for (int st = 0; st < 4; st++){
      int eidx = st * 4 + vg;
      float w = __shfl(e, 4 * min(eidx, cn - 1) + h_v);
      if (eidx >= cn) w = 0.f;
      __half2 w2 = __float2half2_rn(w);
      ch0 = __hfma2(w2, u2h2(vd[st][0]), ch0);
      ch1 = __hfma2(w2, u2h2(vd[st][1]), ch1);
      ch2 = __hfma2(w2, u2h2(vd[st][2]), ch2);
    }
    acc[0] = fmaf(acc[0], rv, __low2float(ch0));
    acc[1] = fmaf(acc[1], rv, __high2float(ch0));
    acc[2] = fmaf(acc[2], rv, __low2float(ch1));
    acc[3] = fmaf(acc[3], rv, __high2float(ch1));
    acc[4] = fmaf(acc[4], rv, __low2float(ch2));
    acc[5] = fmaf(acc[5], rv, __high2float(ch2));
  }

  #pragma unroll
  for (int i = 0; i < 6; i++){
    acc[i] += __shfl_xor(acc[i], 16);
    acc[i] += __shfl_xor(acc[i], 32);
  }
  float sv  = __shfl(s, h_v);
  float inv = (re > rs) ? 1.0f / sv : 0.f;
  float o[6], xr[6];
  #pragma unroll
  for (int i = 0; i < 6; i++) o[i] = acc[i] * inv;
  const float* xrp = qs + (size_t)n * 192 + 96 + 6 * l_v;
  #pragma unroll
  for (int i = 0; i < 6; i++) xr[i] = xrp[i];

  float p = 0.f;
  #pragma unroll
  for (int i = 0; i < 6; i++){
    int f = 6 * l_v + i;
    p += Wb[f] * o[i] + Wb[96 + f] * xr[i] + Wb[192 + f] * (o[i] - xr[i]);
  }
  p += __shfl_xor(p, 1);
  p += __shfl_xor(p, 2);
  p += __shfl_xor(p, 4);
  p += __shfl_xor(p, 8);
  float g = 1.0f / (1.0f + __expf(-p));
  float y[6];
  #pragma unroll
  for (int i = 0; i < 6; i++) y[i] = g * xr[i] + (1.0f - g) * o[i];

  if (mode == 0){
    #pragma unroll
    for (int i = 0; i < 6; i++)
      y[i] = 0.5f * y[i] * (1.0f + erff(y[i] * 0.7071067811865475f));
    if (vg == 0){
      short* op = h1b + (size_t)n * 96 + 6 * l_v;
      #pragma unroll
      for (int i = 0; i < 6; i++) op[i] = f2b(y[i]);
    }
  } else {
    float ssum = y[0] + y[1] + y[2] + y[3] + y[4] + y[5];
    ssum += __shfl_xor(ssum, 1);
    ssum += __shfl_xor(ssum, 2);
    ssum += __shfl_xor(ssum, 4);
    ssum += __shfl_xor(ssum, 8);
    float mu = ssum * (1.0f / 96.0f);
    float vsum = 0.f;
    #pragma unroll
    for (int i = 0; i < 6; i++){ float d = y[i] - mu; vsum += d * d; }
    vsum += __shfl_xor(vsum, 1);
    vsum += __shfl_xor(vsum, 2);
    vsum += __shfl_xor(vsum, 4);
    vsum += __shfl_xor(vsum, 8);
    float invs = rsqrtf(vsum * (1.0f / 96.0f) + 1e-5f);
    if (vg == 0){
      float* op = outp + (size_t)n * 96 + 6 * l_v;
      #pragma unroll
      for (int i = 0; i < 6; i++){
        int f = 6 * l_v + i;
        op[i] = (y[i] - mu) * invs * gamma[f] + beta[f];
      }
    }
  }
}

extern "C" void kernel_launch(void* const* d_in, const int* in_sizes, int n_in,
                              void* d_out, int out_size, void* d_ws, size_t ws_size,
                              hipStream_t stream){
  const float* x    = (const float*)d_in[0];
  const int*   ei   = (const int*)d_in[1];
  const float* Wq1  = (const float*)d_in[2];
  const float* bq1  = (const float*)d_in[3];
  const float* Wk1  = (const float*)d_in[4];
  const float* bk1  = (const float*)d_in[5];
  const float* Wv1  = (const float*)d_in[6];
  const float* bv1  = (const float*)d_in[7];
  const float* Ws1  = (const float*)d_in[8];
  const float* bs1  = (const float*)d_in[9];
  const float* Wb1  = (const float*)d_in[10];
  const float* Wq2  = (const float*)d_in[11];
  const float* bq2  = (const float*)d_in[12];
  const float* Wk2  = (const float*)d_in[13];
  const float* bk2  = (const float*)d_in[14];
  const float* Wv2  = (const float*)d_in[15];
  const float* bv2  = (const float*)d_in[16];
  const float* Ws2  = (const float*)d_in[17];
  const float* bs2  = (const float*)d_in[18];
  const float* Wb2  = (const float*)d_in[19];
  const float* gamma = (const float*)d_in[20];
  const float* beta  = (const float*)d_in[21];
  float* out = (float*)d_out;

  char* ws = (char*)d_ws;
  size_t off = 0;
  auto take = [&](size_t b) -> void* {
    void* p = ws + off;
    off += (b + 255) & ~(size_t)255;
    return p;
  };
  float* qs            = (float*)take((size_t)NN * 192 * 4);
  __half* kvb          = (__half*)take((size_t)NN * 192 * 2);
  short* h1b           = (short*)take((size_t)NN * 96 * 2);
  short* Wcat          = (short*)take((size_t)384 * 128 * 2);
  float* bcat          = (float*)take(384 * 4);
  int* deg             = (int*)take((size_t)NN * 4);
  int* cursor          = (int*)take((size_t)NN * 4);
  int* row_ptr         = (int*)take((size_t)(NN + 1) * 4);
  int* col_src         = (int*)take((size_t)EE * 4);
  int* psum            = (int*)take((size_t)SCAN_NB * 4);

  // CSR build (shared by both layers)
  zero_i32<<<(NN + 255) / 256, 256, 0, stream>>>(deg, NN);
  hist_kernel<<<(EE + 255) / 256, 256, 0, stream>>>(ei, deg);
  partial_sum_kernel<<<SCAN_NB, 256, 0, stream>>>(deg, psum);
  scan_partials_kernel<<<1, 256, 0, stream>>>(psum);
  final_scan_kernel<<<SCAN_NB, 256, 0, stream>>>(deg, psum, row_ptr, cursor);
  fill_kernel<<<(EE + 255) / 256, 256, 0, stream>>>(ei, cursor, col_src);

  dim3 gg((NN + 255) / 256, 3);
  // layer 1 (A = x f32, converted in gemm staging)
  pack_kernel<<<384, 128, 0, stream>>>(Wq1, bq1, Wk1, bk1, Wv1, bv1, Ws1, bs1, Wcat, bcat, 128);
  gemm_kernel<128, true><<<gg, 512, 0, stream>>>(x, Wcat, bcat, qs, kvb, NN);
  attn_kernel<<<(NN + 3) / 4, 256, 0, stream>>>(qs, kvb, row_ptr, col_src, Wb1,
                                                nullptr, nullptr, nullptr, h1b, 0);
  // layer 2 (A = h1b bf16)
  pack_kernel<<<384, 128, 0, stream>>>(Wq2, bq2, Wk2, bk2, Wv2, bv2, Ws2, bs2, Wcat, bcat, 96);
  gemm_kernel<96, false><<<gg, 512, 0, stream>>>(h1b, Wcat, bcat, qs, kvb, NN);
  attn_kernel<<<(NN + 3) / 4, 256, 0, stream>>>(qs, kvb, row_ptr, col_src, Wb2,
                                                gamma, beta, out, nullptr, 1);
}